// Round 1
// baseline (44483.591 us; speedup 1.0000x reference)
//
#include <hip/hip_runtime.h>
#include <cstdint>

typedef uint32_t u32;
typedef _Float16 half2_t __attribute__((ext_vector_type(2)));

static __device__ __forceinline__ u32 pack2(float a, float b) {
    half2_t v;
    v.x = (_Float16)a;
    v.y = (_Float16)b;
    return __builtin_bit_cast(u32, v);
}

static __device__ __forceinline__ float dot2(u32 a, u32 b, float c) {
    return __builtin_amdgcn_fdot2(__builtin_bit_cast(half2_t, a),
                                  __builtin_bit_cast(half2_t, b), c, false);
}

static __device__ __forceinline__ unsigned short f16bits(float v) {
    return __builtin_bit_cast(unsigned short, (_Float16)v);
}

// ---------------------------------------------------------------------------
// RNN kernel: 1 workgroup, 512 threads (8 waves), persistent over T steps.
// thread t: row i = t>>2 (0..127), chunk k = t&3 (input cols 32k..32k+31).
// Weights for all 8 matrices held in VGPRs as f16 pairs (128 VGPRs/thread).
// State hid[4][128] as f16 pairs in LDS, double-buffered per step.
// Circular trick: cur for layer 0 = prev hid[3] (== inp0=0 at step 0 since
// hid[3] starts 0); cur for layer l>0 = this step's hid[l-1].
// ---------------------------------------------------------------------------
__global__ __launch_bounds__(512) void rnn_kernel(
    const float* __restrict__ x0,
    const float* __restrict__ Wih, const float* __restrict__ Whh,
    const float* __restrict__ bih, const float* __restrict__ bhh,
    float* __restrict__ enc, int T)
{
    __shared__ u32 buf[2][4][64];

    const int t = threadIdx.x;
    const int i = t >> 2;   // output row
    const int k = t & 3;    // input chunk (pairs 16k .. 16k+15)

    u32 wih[4][16], whh[4][16];
    float bias[4];
    #pragma unroll
    for (int l = 0; l < 4; ++l) {
        const float* pi = Wih + (size_t)(l * 128 + i) * 128 + k * 32;
        const float* ph = Whh + (size_t)(l * 128 + i) * 128 + k * 32;
        #pragma unroll
        for (int j = 0; j < 16; ++j) {
            wih[l][j] = pack2(pi[2 * j], pi[2 * j + 1]);
            whh[l][j] = pack2(ph[2 * j], ph[2 * j + 1]);
        }
        bias[l] = bih[l * 128 + i] + bhh[l * 128 + i];
    }

    // init: buf[0] = { f16(x), 0, 0, 0 }
    if (t < 256) {
        int layer = t >> 6, p = t & 63;
        buf[0][layer][p] = (layer == 0) ? pack2(x0[2 * p], x0[2 * p + 1]) : 0u;
    }
    __syncthreads();

    int pa = 0;
    for (int s = 0; s < T; ++s) {
        const u32 (*rd)[64] = buf[pa];
        u32 (*wr)[64] = buf[pa ^ 1];
        #pragma unroll
        for (int l = 0; l < 4; ++l) {
            const u32* curp = (l == 0) ? rd[3] : wr[l - 1];
            const u32* hidp = rd[l];
            const u32* cb = curp + k * 16;
            const u32* hb = hidp + k * 16;
            uint4 c0 = *(const uint4*)(cb + 0);
            uint4 c1 = *(const uint4*)(cb + 4);
            uint4 c2 = *(const uint4*)(cb + 8);
            uint4 c3 = *(const uint4*)(cb + 12);
            uint4 g0 = *(const uint4*)(hb + 0);
            uint4 g1 = *(const uint4*)(hb + 4);
            uint4 g2 = *(const uint4*)(hb + 8);
            uint4 g3 = *(const uint4*)(hb + 12);

            float a0 = 0.f, a1 = 0.f, a2 = 0.f, a3 = 0.f;
            a0 = dot2(c0.x, wih[l][0], a0);
            a0 = dot2(c0.y, wih[l][1], a0);
            a0 = dot2(c0.z, wih[l][2], a0);
            a0 = dot2(c0.w, wih[l][3], a0);
            a1 = dot2(c1.x, wih[l][4], a1);
            a1 = dot2(c1.y, wih[l][5], a1);
            a1 = dot2(c1.z, wih[l][6], a1);
            a1 = dot2(c1.w, wih[l][7], a1);
            a2 = dot2(c2.x, wih[l][8], a2);
            a2 = dot2(c2.y, wih[l][9], a2);
            a2 = dot2(c2.z, wih[l][10], a2);
            a2 = dot2(c2.w, wih[l][11], a2);
            a3 = dot2(c3.x, wih[l][12], a3);
            a3 = dot2(c3.y, wih[l][13], a3);
            a3 = dot2(c3.z, wih[l][14], a3);
            a3 = dot2(c3.w, wih[l][15], a3);

            a0 = dot2(g0.x, whh[l][0], a0);
            a0 = dot2(g0.y, whh[l][1], a0);
            a0 = dot2(g0.z, whh[l][2], a0);
            a0 = dot2(g0.w, whh[l][3], a0);
            a1 = dot2(g1.x, whh[l][4], a1);
            a1 = dot2(g1.y, whh[l][5], a1);
            a1 = dot2(g1.z, whh[l][6], a1);
            a1 = dot2(g1.w, whh[l][7], a1);
            a2 = dot2(g2.x, whh[l][8], a2);
            a2 = dot2(g2.y, whh[l][9], a2);
            a2 = dot2(g2.z, whh[l][10], a2);
            a2 = dot2(g2.w, whh[l][11], a2);
            a3 = dot2(g3.x, whh[l][12], a3);
            a3 = dot2(g3.y, whh[l][13], a3);
            a3 = dot2(g3.z, whh[l][14], a3);
            a3 = dot2(g3.w, whh[l][15], a3);

            float v = (a0 + a1) + (a2 + a3);
            v += __shfl_xor(v, 1);
            v += __shfl_xor(v, 2);
            float y = fmaxf(v + bias[l], 0.0f);
            if (k == 0) {
                reinterpret_cast<unsigned short*>(wr[l])[i] = f16bits(y);
                if (l == 3) enc[(size_t)s * 128 + i] = y;
            }
            __syncthreads();
        }
        pa ^= 1;
    }
}

// ---------------------------------------------------------------------------
// Heads kernel: grid (3 heads, T/32 row-segments), 256 threads.
// Per block: 32 rows. x and h staged in LDS as f16 pairs.
// thread: col j = tid&127, row-half rh = tid>>7 (16 rows each).
// W row packed to f16 in VGPRs per matmul; dot via v_dot2_f32_f16.
// ---------------------------------------------------------------------------
__global__ __launch_bounds__(256) void heads_kernel(
    const float* __restrict__ enc,
    const float* __restrict__ arw, const float* __restrict__ arb,
    const float* __restrict__ aw,  const float* __restrict__ ab,
    const float* __restrict__ prw, const float* __restrict__ prb,
    const float* __restrict__ pw,  const float* __restrict__ pb,
    const float* __restrict__ mrw, const float* __restrict__ mrb,
    const float* __restrict__ mw,  const float* __restrict__ mb,
    float* __restrict__ out, int T)
{
    const int head = blockIdx.x;
    const int r0 = blockIdx.y * 32;
    if (r0 >= T) return;

    const float *rbw, *rbb, *ow, *ob;
    int od, oc;
    if (head == 0)      { rbw = arw; rbb = arb; ow = aw; ob = ab; od = 8; oc = 0; }
    else if (head == 1) { rbw = prw; rbb = prb; ow = pw; ob = pb; od = 1; oc = 8; }
    else                { rbw = mrw; rbb = mrb; ow = mw; ob = mb; od = 1; oc = 9; }

    __shared__ u32 xs[32][64];
    __shared__ u32 hs[32][64];

    const int tid = threadIdx.x;

    // stage encodings rows r0..r0+31 as f16 pairs
    #pragma unroll
    for (int rep = 0; rep < 8; ++rep) {
        int u = tid + rep * 256;
        int row = u >> 6, p = u & 63;
        const float* e = enc + (size_t)(r0 + row) * 128 + 2 * p;
        xs[row][p] = pack2(e[0], e[1]);
    }
    __syncthreads();

    const int j = tid & 127;
    const int rh = tid >> 7;

    float acc[16];
    u32 wreg[64];

#define PACKW(WPTR) do {                                                    \
        const float* _w = (WPTR);                                           \
        _Pragma("unroll")                                                   \
        for (int cc = 0; cc < 16; ++cc) {                                   \
            float4 aa = *(const float4*)(_w + cc * 8);                      \
            float4 bb = *(const float4*)(_w + cc * 8 + 4);                  \
            wreg[cc * 4 + 0] = pack2(aa.x, aa.y);                           \
            wreg[cc * 4 + 1] = pack2(aa.z, aa.w);                           \
            wreg[cc * 4 + 2] = pack2(bb.x, bb.y);                           \
            wreg[cc * 4 + 3] = pack2(bb.z, bb.w);                           \
        }                                                                   \
    } while (0)

#define MM16(SRC) do {                                                      \
        _Pragma("unroll")                                                   \
        for (int r = 0; r < 16; ++r) acc[r] = 0.f;                          \
        _Pragma("unroll")                                                   \
        for (int kp = 0; kp < 16; ++kp) {                                   \
            u32 w0 = wreg[kp * 4 + 0], w1 = wreg[kp * 4 + 1];               \
            u32 w2 = wreg[kp * 4 + 2], w3 = wreg[kp * 4 + 3];               \
            _Pragma("unroll")                                               \
            for (int r = 0; r < 16; ++r) {                                  \
                uint4 x4 = *(const uint4*)(&SRC[rh * 16 + r][kp * 4]);      \
                acc[r] = dot2(x4.x, w0, acc[r]);                            \
                acc[r] = dot2(x4.y, w1, acc[r]);                            \
                acc[r] = dot2(x4.z, w2, acc[r]);                            \
                acc[r] = dot2(x4.w, w3, acc[r]);                            \
            }                                                               \
        }                                                                   \
    } while (0)

    #pragma unroll
    for (int blk = 0; blk < 2; ++blk) {
        // pass 1: hs = leaky_relu(xs @ W1^T + b1)
        PACKW(rbw + (size_t)((blk * 2 + 0) * 128 + j) * 128);
        MM16(xs);
        {
            float b1 = rbb[(blk * 2 + 0) * 128 + j];
            #pragma unroll
            for (int r = 0; r < 16; ++r) {
                float v = acc[r] + b1;
                v = fmaxf(v, 0.2f * v);
                reinterpret_cast<unsigned short*>(&hs[rh * 16 + r][0])[j] = f16bits(v);
            }
        }
        __syncthreads();

        // pass 2: xs = leaky_relu(xs + hs @ W2^T + b2)
        PACKW(rbw + (size_t)((blk * 2 + 1) * 128 + j) * 128);
        MM16(hs);
        {
            float b2 = rbb[(blk * 2 + 1) * 128 + j];
            #pragma unroll
            for (int r = 0; r < 16; ++r) {
                int row = rh * 16 + r;
                unsigned short xb =
                    reinterpret_cast<const unsigned short*>(&xs[row][0])[j];
                float xold = (float)__builtin_bit_cast(_Float16, xb);
                float v = xold + acc[r] + b2;
                v = fmaxf(v, 0.2f * v);
                reinterpret_cast<unsigned short*>(&xs[row][0])[j] = f16bits(v);
            }
        }
        __syncthreads();
    }

    // out layer: out[r, oc+o] = xs[r] . ow[o] + ob[o]
    {
        const int o = tid & 15;
        const int rr = tid >> 4;   // 0..15 -> rows rr*2, rr*2+1
        if (o < od) {
            PACKW(ow + (size_t)o * 128);
            float obv = ob[o];
            #pragma unroll
            for (int rs = 0; rs < 2; ++rs) {
                const int row = rr * 2 + rs;
                float a = 0.f;
                #pragma unroll
                for (int kp = 0; kp < 64; ++kp) a = dot2(xs[row][kp], wreg[kp], a);
                out[(size_t)(r0 + row) * 10 + oc + o] = a + obv;
            }
        }
    }
#undef PACKW
#undef MM16
}

extern "C" void kernel_launch(void* const* d_in, const int* in_sizes, int n_in,
                              void* d_out, int out_size, void* d_ws, size_t ws_size,
                              hipStream_t stream)
{
    const float* x   = (const float*)d_in[0];
    const float* Wih = (const float*)d_in[1];
    const float* Whh = (const float*)d_in[2];
    const float* bih = (const float*)d_in[3];
    const float* bhh = (const float*)d_in[4];
    const float* arw = (const float*)d_in[5];
    const float* arb = (const float*)d_in[6];
    const float* aw  = (const float*)d_in[7];
    const float* ab  = (const float*)d_in[8];
    const float* prw = (const float*)d_in[9];
    const float* prb = (const float*)d_in[10];
    const float* pw  = (const float*)d_in[11];
    const float* pb  = (const float*)d_in[12];
    const float* mrw = (const float*)d_in[13];
    const float* mrb = (const float*)d_in[14];
    const float* mw  = (const float*)d_in[15];
    const float* mb  = (const float*)d_in[16];

    const int T = out_size / 10;             // 32768
    float* enc = (float*)d_ws;               // T*128 fp32 = 16 MB scratch

    rnn_kernel<<<1, 512, 0, stream>>>(x, Wih, Whh, bih, bhh, enc, T);

    heads_kernel<<<dim3(3, (T + 31) / 32), 256, 0, stream>>>(
        enc, arw, arb, aw, ab, prw, prb, pw, pb, mrw, mrb, mw, mb,
        (float*)d_out, T);
}